// Round 5
// baseline (443.933 us; speedup 1.0000x reference)
//
#include <hip/hip_runtime.h>
#include <hip/hip_bf16.h>

typedef __bf16 bf16;
typedef __bf16 bf16x4 __attribute__((ext_vector_type(4)));
typedef __bf16 bf16x8 __attribute__((ext_vector_type(8)));
typedef short  s16x4  __attribute__((ext_vector_type(4)));
typedef float  f32x4  __attribute__((ext_vector_type(4)));

#define MFMA_16x16x32(a, b, c) __builtin_amdgcn_mfma_f32_16x16x32_bf16((a), (b), (c), 0, 0, 0)

__device__ __forceinline__ f32x4 MFMA16x16x16(bf16x4 a, bf16x4 b, f32x4 c) {
#if __has_builtin(__builtin_amdgcn_mfma_f32_16x16x16_bf16)
    return __builtin_amdgcn_mfma_f32_16x16x16_bf16(a, b, c, 0, 0, 0);
#else
    union U { bf16x4 h; s16x4 s; };
    U ua, ub; ua.h = a; ub.h = b;
    return __builtin_amdgcn_mfma_f32_16x16x16bf16_1k(ua.s, ub.s, c, 0, 0, 0);
#endif
}

typedef const void __attribute__((address_space(1))) gvoid;
typedef void __attribute__((address_space(3))) svoid;

__device__ __forceinline__ void async_copy16(const void* gptr, void* ldsptr) {
    __builtin_amdgcn_global_load_lds((gvoid*)gptr, (svoid*)ldsptr, 16, 0, 0);
}

// ---------------------------------------------------------------------------
// Fused f32->bf16 converters.
// ---------------------------------------------------------------------------
__global__ void cvt3_acts(const float* __restrict__ s0, const float* __restrict__ s1,
                          const float* __restrict__ s2,
                          bf16* __restrict__ d0, bf16* __restrict__ d1, bf16* __restrict__ d2)
{
    constexpr int N4SEG = 8192 * 1024 / 4;
    int i = blockIdx.x * blockDim.x + threadIdx.x;
    const int stride = gridDim.x * blockDim.x;
    for (; i < 3 * N4SEG; i += stride) {
        const int seg = i / N4SEG;
        const int j = i - seg * N4SEG;
        const float* s = seg == 0 ? s0 : (seg == 1 ? s1 : s2);
        bf16* d = seg == 0 ? d0 : (seg == 1 ? d1 : d2);
        float4 v = ((const float4*)s)[j];
        bf16x4 o = { (bf16)v.x, (bf16)v.y, (bf16)v.z, (bf16)v.w };
        ((bf16x4*)d)[j] = o;
    }
}

__global__ void cvt5_wts(const float* __restrict__ s0, const float* __restrict__ s1,
                         const float* __restrict__ s2, const float* __restrict__ s3,
                         const float* __restrict__ s4,
                         bf16* __restrict__ d0, bf16* __restrict__ d1, bf16* __restrict__ d2,
                         bf16* __restrict__ d3, bf16* __restrict__ d4)
{
    constexpr int N4SEG = 1024 * 1024 / 4;
    int i = blockIdx.x * blockDim.x + threadIdx.x;
    const int stride = gridDim.x * blockDim.x;
    for (; i < 5 * N4SEG; i += stride) {
        const int seg = i / N4SEG;
        const int j = i - seg * N4SEG;
        const float* s = seg == 0 ? s0 : seg == 1 ? s1 : seg == 2 ? s2 : seg == 3 ? s3 : s4;
        bf16* d = seg == 0 ? d0 : seg == 1 ? d1 : seg == 2 ? d2 : seg == 3 ? d3 : d4;
        float4 v = ((const float4*)s)[j];
        bf16x4 o = { (bf16)v.x, (bf16)v.y, (bf16)v.z, (bf16)v.w };
        ((bf16x4*)d)[j] = o;
    }
}

// ---------------------------------------------------------------------------
// NT GEMM: Y[m][n] = sum_k X[m][k] * W[n][k] + bias[n]
// 128x128 tile, BK=32, 256 threads (4 waves, 2x2, 64x64 each).
// TRANS=true writes Y transposed per batch: Yt[b][n][s], m = b*2048 + s.
// ---------------------------------------------------------------------------
template <typename OutT, bool TRANS>
__global__ void gemm_nt_bias(const bf16* __restrict__ X, const bf16* __restrict__ W,
                             const float* __restrict__ bias, OutT* __restrict__ Y,
                             int M, int N, int K)
{
    constexpr int SDIM = 2048;
    __shared__ alignas(16) bf16 As[128 * 32];
    __shared__ alignas(16) bf16 Bs[128 * 32];

    const int tid  = threadIdx.x;
    const int lane = tid & 63;
    const int wave = tid >> 6;
    const int wm   = wave >> 1;
    const int wn   = wave & 1;
    const int bm   = blockIdx.x * 128;
    const int bn   = blockIdx.y * 128;
    const int l15  = lane & 15;
    const int quad = lane >> 4;

    const int srow = lane >> 2;
    const int scol = (lane & 3) * 8;

    const bf16* aseg0 = X + (size_t)(bm + wave * 32 + srow) * K + scol;
    const bf16* aseg1 = X + (size_t)(bm + wave * 32 + 16 + srow) * K + scol;
    const bf16* bseg0 = W + (size_t)(bn + wave * 32 + srow) * K + scol;
    const bf16* bseg1 = W + (size_t)(bn + wave * 32 + 16 + srow) * K + scol;
    bf16* as0 = As + (wave * 2 + 0) * 512;
    bf16* as1 = As + (wave * 2 + 1) * 512;
    bf16* bs0 = Bs + (wave * 2 + 0) * 512;
    bf16* bs1 = Bs + (wave * 2 + 1) * 512;

    f32x4 acc[4][4] = {};

    for (int k0 = 0; k0 < K; k0 += 32) {
        __syncthreads();
        async_copy16(aseg0 + k0, as0);
        async_copy16(aseg1 + k0, as1);
        async_copy16(bseg0 + k0, bs0);
        async_copy16(bseg1 + k0, bs1);
        __syncthreads();

        bf16x8 af[4], bfr[4];
        #pragma unroll
        for (int i = 0; i < 4; ++i)
            af[i] = *(const bf16x8*)(As + (wm * 64 + i * 16 + l15) * 32 + quad * 8);
        #pragma unroll
        for (int j = 0; j < 4; ++j)
            bfr[j] = *(const bf16x8*)(Bs + (wn * 64 + j * 16 + l15) * 32 + quad * 8);
        #pragma unroll
        for (int i = 0; i < 4; ++i)
            #pragma unroll
            for (int j = 0; j < 4; ++j)
                acc[i][j] = MFMA_16x16x32(af[i], bfr[j], acc[i][j]);
    }

    #pragma unroll
    for (int i = 0; i < 4; ++i) {
        const int rowg = bm + wm * 64 + i * 16 + quad * 4;
        #pragma unroll
        for (int j = 0; j < 4; ++j) {
            const int colg = bn + wn * 64 + j * 16 + l15;
            const float bv = bias[colg];
            if (TRANS) {
                bf16x4 o;
                #pragma unroll
                for (int r = 0; r < 4; ++r) o[r] = (bf16)(acc[i][j][r] + bv);
                *(bf16x4*)((bf16*)Y + (size_t)(rowg >> 11) * N * SDIM
                                    + (size_t)colg * SDIM + (rowg & (SDIM - 1))) = o;
            } else {
                #pragma unroll
                for (int r = 0; r < 4; ++r)
                    Y[(size_t)(rowg + r) * N + colg] = (OutT)(acc[i][j][r] + bv);
            }
        }
    }
}

// ---------------------------------------------------------------------------
// Streaming attention + R-gating, REGISTER-RESIDENT P.
// Block = (b, h, 128 q-rows); 4 waves x 32 q-rows (mi=2). KV tiles of 64.
// QK^T computed TRANSPOSED (A=K, B=Q — same fragment bytes, swapped roles):
// C-layout gives P^T[kv][qrow] with col=qrow=l15, row=kv=quad*4+r — which is
// exactly the 16x16x16 MFMA B-fragment layout (k=quad*4+j, n=l15). So
// exp2(S^T) packs straight into the PV MFMA's B operand: no LDS round-trip,
// no scalar ds_writes. PV uses A=Vt fragments (b64 LDS reads), producing
// O^T[d][qrow] (col=qrow): one rcp per lane, contiguous bf16x4 R-load/O-store.
// lsum accumulated per-lane in fp32, reduced with 2 shuffles at the end.
// ---------------------------------------------------------------------------
__launch_bounds__(256, 4)
__global__ void attn_fused(const bf16* __restrict__ QRp, const bf16* __restrict__ Kp,
                           const bf16* __restrict__ Vtp, bf16* __restrict__ Op)
{
    constexpr int S = 2048, DXc = 1024, QRST = 2048, Dh = 64;
    __shared__ alignas(16) bf16 KsLo[64 * 32], KsHi[64 * 32];
    __shared__ alignas(16) bf16 VtLo[64 * 32], VtHi[64 * 32];

    const int tid  = threadIdx.x;
    const int lane = tid & 63;
    const int wave = tid >> 6;
    const int qt = blockIdx.x, h = blockIdx.y, b = blockIdx.z;
    const int l15  = lane & 15;
    const int quad = lane >> 4;

    const size_t qrbase = ((size_t)b * S) * QRST + h * Dh;   // Q cols; R at +1024
    const size_t kbase  = ((size_t)b * S) * DXc + h * Dh;
    const size_t vtbase = ((size_t)(b * 16 + h) * Dh) * S;
    const size_t obase  = ((size_t)b * S) * DXc + h * Dh;

    // Q fragments, prescaled by 0.125*log2(e) for exp2-domain softmax
    constexpr float QSCALE = 0.125f * 1.44269504088896340736f;
    bf16x8 qf[2][2];
    #pragma unroll
    for (int mi = 0; mi < 2; ++mi) {
        const int qrow = qt * 128 + wave * 32 + mi * 16 + l15;
        const bf16* qptr = QRp + qrbase + (size_t)qrow * QRST + quad * 8;
        qf[mi][0] = *(const bf16x8*)(qptr);
        qf[mi][1] = *(const bf16x8*)(qptr + 32);
        #pragma unroll
        for (int j = 0; j < 8; ++j) {
            qf[mi][0][j] = (bf16)((float)qf[mi][0][j] * QSCALE);
            qf[mi][1][j] = (bf16)((float)qf[mi][1][j] * QSCALE);
        }
    }

    f32x4 oacc[2][4] = {};     // [mi][db] — O^T: col=qrow(l15), rows d=quad*4+r
    float lsum[2] = {0.f, 0.f};

    const int srow = lane >> 2;
    const int scol = (lane & 3) * 8;
    const bf16* kseg = Kp  + kbase  + (size_t)(16 * wave + srow) * DXc + scol;
    const bf16* vseg = Vtp + vtbase + (size_t)(16 * wave + srow) * S   + scol;
    bf16* ksl = KsLo + wave * 512;
    bf16* ksh = KsHi + wave * 512;
    bf16* vtl = VtLo + wave * 512;
    bf16* vth = VtHi + wave * 512;

    for (int kv0 = 0; kv0 < S; kv0 += 64) {
        __syncthreads();
        async_copy16(kseg + (size_t)kv0 * DXc,      ksl);
        async_copy16(kseg + (size_t)kv0 * DXc + 32, ksh);
        async_copy16(vseg + kv0,                    vtl);
        async_copy16(vseg + kv0 + 32,               vth);
        __syncthreads();

        #pragma unroll
        for (int nb = 0; nb < 4; ++nb) {
            // K fragments for this 16-kv block (dual role: A-operand now)
            bf16x8 kf0 = *(const bf16x8*)(KsLo + (nb * 16 + l15) * 32 + quad * 8);
            bf16x8 kf1 = *(const bf16x8*)(KsHi + (nb * 16 + l15) * 32 + quad * 8);
            // Vt fragments for this kv-chunk: lane needs Vt[db*16+l15][nb*16+quad*4 ..+3]
            const bf16* vbase = (nb < 2) ? VtLo : VtHi;
            const int vcol = (nb & 1) * 16 + quad * 4;
            bf16x4 vtf[4];
            #pragma unroll
            for (int db = 0; db < 4; ++db)
                vtf[db] = *(const bf16x4*)(vbase + (db * 16 + l15) * 32 + vcol);

            #pragma unroll
            for (int mi = 0; mi < 2; ++mi) {
                // S^T block: D[kv][qrow], col=qrow=l15, row=kv=quad*4+r
                f32x4 z = {0.f, 0.f, 0.f, 0.f};
                z = MFMA_16x16x32(kf1, qf[mi][1], z);
                z = MFMA_16x16x32(kf0, qf[mi][0], z);
                // exp2 -> B-fragment of P^T (k=quad*4+r, n=l15) directly
                bf16x4 pt;
                #pragma unroll
                for (int r = 0; r < 4; ++r) {
                    float p = __builtin_exp2f(z[r]);
                    lsum[mi] += p;
                    pt[r] = (bf16)p;
                }
                #pragma unroll
                for (int db = 0; db < 4; ++db)
                    oacc[mi][db] = MFMA16x16x16(vtf[db], pt, oacc[mi][db]);
            }
        }
    }

    // lsum: lane covers its quad's kv rows; reduce across quads (same l15)
    #pragma unroll
    for (int mi = 0; mi < 2; ++mi) {
        lsum[mi] += __shfl_xor(lsum[mi], 16, 64);
        lsum[mi] += __shfl_xor(lsum[mi], 32, 64);
    }

    // epilogue: O^T col=qrow=l15 for ALL regs of a mi -> single inv;
    // rows d=db*16+quad*4+r -> contiguous bf16x4 R-loads and O-stores
    #pragma unroll
    for (int mi = 0; mi < 2; ++mi) {
        const float inv = 1.0f / lsum[mi];
        const int qrow = qt * 128 + wave * 32 + mi * 16 + l15;
        const bf16* rrow = QRp + qrbase + (size_t)qrow * QRST + 1024;
        bf16* orow = Op + obase + (size_t)qrow * DXc;
        #pragma unroll
        for (int db = 0; db < 4; ++db) {
            bf16x4 rg = *(const bf16x4*)(rrow + db * 16 + quad * 4);
            bf16x4 o;
            #pragma unroll
            for (int r = 0; r < 4; ++r)
                o[r] = (bf16)(oacc[mi][db][r] * inv * (float)rg[r]);
            *(bf16x4*)(orow + db * 16 + quad * 4) = o;
        }
    }
}

extern "C" void kernel_launch(void* const* d_in, const int* in_sizes, int n_in,
                              void* d_out, int out_size, void* d_ws, size_t ws_size,
                              hipStream_t stream)
{
    (void)in_sizes; (void)n_in; (void)out_size; (void)ws_size;
    constexpr int B = 4, S = 2048, DX = 1024, M = B * S;
    constexpr size_t MD = (size_t)M * DX;
    constexpr size_t WD = (size_t)DX * DX;

    const float* value  = (const float*)d_in[0];
    const float* keyi   = (const float*)d_in[1];
    const float* query  = (const float*)d_in[2];
    const float* Wq_w   = (const float*)d_in[3];
    const float* Wq_b   = (const float*)d_in[4];
    const float* Wk_w   = (const float*)d_in[5];
    const float* Wk_b   = (const float*)d_in[6];
    const float* Wv_w   = (const float*)d_in[7];
    const float* Wv_b   = (const float*)d_in[8];
    const float* Wr_w   = (const float*)d_in[9];
    const float* Wr_b   = (const float*)d_in[10];
    const float* Wout_w = (const float*)d_in[11];
    const float* Wout_b = (const float*)d_in[12];

    bf16* p = (bf16*)d_ws;
    bf16* xv  = p;  p += MD;
    bf16* xk  = p;  p += MD;
    bf16* xq  = p;  p += MD;
    bf16* wqr = p;  p += 2 * WD;   // [Wq; Wr]
    bf16* wk  = p;  p += WD;
    bf16* wv  = p;  p += WD;
    bf16* wo  = p;  p += WD;
    bf16* qr  = p;  p += 2 * MD;   // fused Q|R output, [M][2048]
    bf16* kws = p;  p += MD;
    bf16* vtws= p;  p += MD;       // V^T: [B][DX][S]
    float* qrb = (float*)p;        // fused bias [2048]
    bf16* ows = xv;                // xv dead after V projection

    hipMemcpyAsync(qrb,      Wq_b, DX * sizeof(float), hipMemcpyDeviceToDevice, stream);
    hipMemcpyAsync(qrb + DX, Wr_b, DX * sizeof(float), hipMemcpyDeviceToDevice, stream);

    cvt3_acts<<<dim3(2048), dim3(256), 0, stream>>>(value, keyi, query, xv, xk, xq);
    cvt5_wts <<<dim3(1024), dim3(256), 0, stream>>>(Wq_w, Wr_w, Wk_w, Wv_w, Wout_w,
                                                    wqr, wqr + WD, wk, wv, wo);

    dim3 gblk(256);
    gemm_nt_bias<bf16, false><<<dim3(M / 128, 2048 / 128), gblk, 0, stream>>>(
        xq, wqr, qrb, qr, M, 2048, DX);
    gemm_nt_bias<bf16, false><<<dim3(M / 128, DX / 128), gblk, 0, stream>>>(
        xk, wk, Wk_b, kws, M, DX, DX);
    gemm_nt_bias<bf16, true ><<<dim3(M / 128, DX / 128), gblk, 0, stream>>>(
        xv, wv, Wv_b, vtws, M, DX, DX);

    attn_fused<<<dim3(S / 128, 16, B), gblk, 0, stream>>>(qr, kws, vtws, ows);

    gemm_nt_bias<float, false><<<dim3(M / 128, DX / 128), gblk, 0, stream>>>(
        ows, wo, Wout_b, (float*)d_out, M, DX, DX);
}

// Round 6
// 397.743 us; speedup vs baseline: 1.1161x; 1.1161x over previous
//
#include <hip/hip_runtime.h>
#include <hip/hip_bf16.h>

typedef __bf16 bf16;
typedef __bf16 bf16x4 __attribute__((ext_vector_type(4)));
typedef __bf16 bf16x8 __attribute__((ext_vector_type(8)));
typedef float  f32x4  __attribute__((ext_vector_type(4)));

#define MFMA_16x16x32(a, b, c) __builtin_amdgcn_mfma_f32_16x16x32_bf16((a), (b), (c), 0, 0, 0)

typedef const void __attribute__((address_space(1))) gvoid;
typedef void __attribute__((address_space(3))) svoid;

__device__ __forceinline__ void async_copy16(const void* gptr, void* ldsptr) {
    __builtin_amdgcn_global_load_lds((gvoid*)gptr, (svoid*)ldsptr, 16, 0, 0);
}

// ---------------------------------------------------------------------------
// Fused f32->bf16 converters.
// ---------------------------------------------------------------------------
__global__ void cvt3_acts(const float* __restrict__ s0, const float* __restrict__ s1,
                          const float* __restrict__ s2,
                          bf16* __restrict__ d0, bf16* __restrict__ d1, bf16* __restrict__ d2)
{
    constexpr int N4SEG = 8192 * 1024 / 4;
    int i = blockIdx.x * blockDim.x + threadIdx.x;
    const int stride = gridDim.x * blockDim.x;
    for (; i < 3 * N4SEG; i += stride) {
        const int seg = i / N4SEG;
        const int j = i - seg * N4SEG;
        const float* s = seg == 0 ? s0 : (seg == 1 ? s1 : s2);
        bf16* d = seg == 0 ? d0 : (seg == 1 ? d1 : d2);
        float4 v = ((const float4*)s)[j];
        bf16x4 o = { (bf16)v.x, (bf16)v.y, (bf16)v.z, (bf16)v.w };
        ((bf16x4*)d)[j] = o;
    }
}

__global__ void cvt5_wts(const float* __restrict__ s0, const float* __restrict__ s1,
                         const float* __restrict__ s2, const float* __restrict__ s3,
                         const float* __restrict__ s4,
                         bf16* __restrict__ d0, bf16* __restrict__ d1, bf16* __restrict__ d2,
                         bf16* __restrict__ d3, bf16* __restrict__ d4)
{
    constexpr int N4SEG = 1024 * 1024 / 4;
    int i = blockIdx.x * blockDim.x + threadIdx.x;
    const int stride = gridDim.x * blockDim.x;
    for (; i < 5 * N4SEG; i += stride) {
        const int seg = i / N4SEG;
        const int j = i - seg * N4SEG;
        const float* s = seg == 0 ? s0 : seg == 1 ? s1 : seg == 2 ? s2 : seg == 3 ? s3 : s4;
        bf16* d = seg == 0 ? d0 : seg == 1 ? d1 : seg == 2 ? d2 : seg == 3 ? d3 : d4;
        float4 v = ((const float4*)s)[j];
        bf16x4 o = { (bf16)v.x, (bf16)v.y, (bf16)v.z, (bf16)v.w };
        ((bf16x4*)d)[j] = o;
    }
}

// ---------------------------------------------------------------------------
// Fused projection GEMM, one dispatch for QR | K | V^T.
// Global n in [0,4096): [0,2048)=QR -> qr[M][2048]; [2048,3072)=K -> kws;
// [3072,4096)=V -> vtws transposed per batch. X selected per region.
// Weights packed wall[4096][1024] = [Wq;Wr;Wk;Wv]; bias ball[4096] f32.
// ---------------------------------------------------------------------------
__global__ void proj_fused(const bf16* __restrict__ xq, const bf16* __restrict__ xk,
                           const bf16* __restrict__ xv, const bf16* __restrict__ wall,
                           const float* __restrict__ ball,
                           bf16* __restrict__ qr, bf16* __restrict__ kws,
                           bf16* __restrict__ vtws)
{
    constexpr int K = 1024, SDIM = 2048;
    __shared__ alignas(16) bf16 As[128 * 32];
    __shared__ alignas(16) bf16 Bs[128 * 32];

    const int tid  = threadIdx.x;
    const int lane = tid & 63;
    const int wave = tid >> 6;
    const int wm   = wave >> 1;
    const int wn   = wave & 1;
    const int bm   = blockIdx.x * 128;
    const int by   = blockIdx.y;
    const int bn   = by * 128;              // global n
    const int l15  = lane & 15;
    const int quad = lane >> 4;

    const bf16* X = (by < 16) ? xq : (by < 24 ? xk : xv);

    const int srow = lane >> 2;
    const int scol = (lane & 3) * 8;

    const bf16* aseg0 = X + (size_t)(bm + wave * 32 + srow) * K + scol;
    const bf16* aseg1 = X + (size_t)(bm + wave * 32 + 16 + srow) * K + scol;
    const bf16* bseg0 = wall + (size_t)(bn + wave * 32 + srow) * K + scol;
    const bf16* bseg1 = wall + (size_t)(bn + wave * 32 + 16 + srow) * K + scol;
    bf16* as0 = As + (wave * 2 + 0) * 512;
    bf16* as1 = As + (wave * 2 + 1) * 512;
    bf16* bs0 = Bs + (wave * 2 + 0) * 512;
    bf16* bs1 = Bs + (wave * 2 + 1) * 512;

    f32x4 acc[4][4] = {};

    for (int k0 = 0; k0 < K; k0 += 32) {
        __syncthreads();
        async_copy16(aseg0 + k0, as0);
        async_copy16(aseg1 + k0, as1);
        async_copy16(bseg0 + k0, bs0);
        async_copy16(bseg1 + k0, bs1);
        __syncthreads();

        bf16x8 af[4], bfr[4];
        #pragma unroll
        for (int i = 0; i < 4; ++i)
            af[i] = *(const bf16x8*)(As + (wm * 64 + i * 16 + l15) * 32 + quad * 8);
        #pragma unroll
        for (int j = 0; j < 4; ++j)
            bfr[j] = *(const bf16x8*)(Bs + (wn * 64 + j * 16 + l15) * 32 + quad * 8);
        #pragma unroll
        for (int i = 0; i < 4; ++i)
            #pragma unroll
            for (int j = 0; j < 4; ++j)
                acc[i][j] = MFMA_16x16x32(af[i], bfr[j], acc[i][j]);
    }

    #pragma unroll
    for (int i = 0; i < 4; ++i) {
        const int rowg = bm + wm * 64 + i * 16 + quad * 4;
        #pragma unroll
        for (int j = 0; j < 4; ++j) {
            const int colg = bn + wn * 64 + j * 16 + l15;
            const float bv = ball[colg];
            if (by < 16) {
                #pragma unroll
                for (int r = 0; r < 4; ++r)
                    qr[(size_t)(rowg + r) * 2048 + colg] = (bf16)(acc[i][j][r] + bv);
            } else if (by < 24) {
                const int cl = colg - 2048;
                #pragma unroll
                for (int r = 0; r < 4; ++r)
                    kws[(size_t)(rowg + r) * 1024 + cl] = (bf16)(acc[i][j][r] + bv);
            } else {
                const int d = colg - 3072;
                bf16x4 o;
                #pragma unroll
                for (int r = 0; r < 4; ++r) o[r] = (bf16)(acc[i][j][r] + bv);
                *(bf16x4*)(vtws + (size_t)(rowg >> 11) * 1024 * SDIM
                                + (size_t)d * SDIM + (rowg & (SDIM - 1))) = o;
            }
        }
    }
}

// ---------------------------------------------------------------------------
// Output GEMM: Y[m][n] = sum_k X[m][k]*W[n][k] + b[n], f32 out.
// ---------------------------------------------------------------------------
__global__ void gemm_out(const bf16* __restrict__ X, const bf16* __restrict__ W,
                         const float* __restrict__ bias, float* __restrict__ Y)
{
    constexpr int K = 1024, N = 1024;
    __shared__ alignas(16) bf16 As[128 * 32];
    __shared__ alignas(16) bf16 Bs[128 * 32];

    const int tid  = threadIdx.x;
    const int lane = tid & 63;
    const int wave = tid >> 6;
    const int wm   = wave >> 1;
    const int wn   = wave & 1;
    const int bm   = blockIdx.x * 128;
    const int bn   = blockIdx.y * 128;
    const int l15  = lane & 15;
    const int quad = lane >> 4;

    const int srow = lane >> 2;
    const int scol = (lane & 3) * 8;

    const bf16* aseg0 = X + (size_t)(bm + wave * 32 + srow) * K + scol;
    const bf16* aseg1 = X + (size_t)(bm + wave * 32 + 16 + srow) * K + scol;
    const bf16* bseg0 = W + (size_t)(bn + wave * 32 + srow) * K + scol;
    const bf16* bseg1 = W + (size_t)(bn + wave * 32 + 16 + srow) * K + scol;
    bf16* as0 = As + (wave * 2 + 0) * 512;
    bf16* as1 = As + (wave * 2 + 1) * 512;
    bf16* bs0 = Bs + (wave * 2 + 0) * 512;
    bf16* bs1 = Bs + (wave * 2 + 1) * 512;

    f32x4 acc[4][4] = {};

    for (int k0 = 0; k0 < K; k0 += 32) {
        __syncthreads();
        async_copy16(aseg0 + k0, as0);
        async_copy16(aseg1 + k0, as1);
        async_copy16(bseg0 + k0, bs0);
        async_copy16(bseg1 + k0, bs1);
        __syncthreads();

        bf16x8 af[4], bfr[4];
        #pragma unroll
        for (int i = 0; i < 4; ++i)
            af[i] = *(const bf16x8*)(As + (wm * 64 + i * 16 + l15) * 32 + quad * 8);
        #pragma unroll
        for (int j = 0; j < 4; ++j)
            bfr[j] = *(const bf16x8*)(Bs + (wn * 64 + j * 16 + l15) * 32 + quad * 8);
        #pragma unroll
        for (int i = 0; i < 4; ++i)
            #pragma unroll
            for (int j = 0; j < 4; ++j)
                acc[i][j] = MFMA_16x16x32(af[i], bfr[j], acc[i][j]);
    }

    #pragma unroll
    for (int i = 0; i < 4; ++i) {
        const int rowg = bm + wm * 64 + i * 16 + quad * 4;
        #pragma unroll
        for (int j = 0; j < 4; ++j) {
            const int colg = bn + wn * 64 + j * 16 + l15;
            const float bv = bias[colg];
            #pragma unroll
            for (int r = 0; r < 4; ++r)
                Y[(size_t)(rowg + r) * N + colg] = acc[i][j][r] + bv;
        }
    }
}

// ---------------------------------------------------------------------------
// Streaming attention + R-gating. Block = (b, h, 128 q-rows); 4 waves x 32
// q-rows (mi=2). KV tiles of 64, staged lo/hi via global_load_lds.
// S computed TRANSPOSED (A=K, B=Q): C-layout = P^T[kv][qrow], col=qrow=l15,
// rows kv=quad*4+r -> packs to ONE ds_write_b64 per 16x16 block into a
// per-wave [qrow][kv] buffer, row stride 40 elems (80B: conflict-free for
// both b64 writes and b128 reads; 16B-aligned). PV at K=32: B-frag of P^T is
// ds_read_b128 (row l15, cols quad*8), A=Vt b128 frags. Output is O^T
// (col=qrow): one rcp per (mi,lane), contiguous bf16x4 R-gate + store.
// lsum per-lane f32, reduced with 2 shuffles.
// ---------------------------------------------------------------------------
__launch_bounds__(256, 4)
__global__ void attn_fused(const bf16* __restrict__ QRp, const bf16* __restrict__ Kp,
                           const bf16* __restrict__ Vtp, bf16* __restrict__ Op)
{
    constexpr int S = 2048, DXc = 1024, QRST = 2048, Dh = 64;
    constexpr int PST = 40;                     // P^T row stride (elements)
    __shared__ alignas(16) bf16 KsLo[64 * 32], KsHi[64 * 32];
    __shared__ alignas(16) bf16 VtLo[64 * 32], VtHi[64 * 32];
    __shared__ alignas(16) bf16 Pt[4][2][2][16 * PST];   // [wave][mi][half]

    const int tid  = threadIdx.x;
    const int lane = tid & 63;
    const int wave = tid >> 6;
    const int qt = blockIdx.x, h = blockIdx.y, b = blockIdx.z;
    const int l15  = lane & 15;
    const int quad = lane >> 4;

    const size_t qrbase = ((size_t)b * S) * QRST + h * Dh;   // Q cols; R at +1024
    const size_t kbase  = ((size_t)b * S) * DXc + h * Dh;
    const size_t vtbase = ((size_t)(b * 16 + h) * Dh) * S;
    const size_t obase  = ((size_t)b * S) * DXc + h * Dh;

    constexpr float QSCALE = 0.125f * 1.44269504088896340736f;
    bf16x8 qf[2][2];
    #pragma unroll
    for (int mi = 0; mi < 2; ++mi) {
        const int qrow = qt * 128 + wave * 32 + mi * 16 + l15;
        const bf16* qptr = QRp + qrbase + (size_t)qrow * QRST + quad * 8;
        qf[mi][0] = *(const bf16x8*)(qptr);
        qf[mi][1] = *(const bf16x8*)(qptr + 32);
        #pragma unroll
        for (int j = 0; j < 8; ++j) {
            qf[mi][0][j] = (bf16)((float)qf[mi][0][j] * QSCALE);
            qf[mi][1][j] = (bf16)((float)qf[mi][1][j] * QSCALE);
        }
    }

    f32x4 oacc[2][4] = {};     // [mi][db] — O^T: col=qrow(l15), rows d=quad*4+r
    float lsum[2] = {0.f, 0.f};

    const int srow = lane >> 2;
    const int scol = (lane & 3) * 8;
    const bf16* kseg = Kp  + kbase  + (size_t)(16 * wave + srow) * DXc + scol;
    const bf16* vseg = Vtp + vtbase + (size_t)(16 * wave + srow) * S   + scol;
    bf16* ksl = KsLo + wave * 512;
    bf16* ksh = KsHi + wave * 512;
    bf16* vtl = VtLo + wave * 512;
    bf16* vth = VtHi + wave * 512;

    for (int kv0 = 0; kv0 < S; kv0 += 64) {
        __syncthreads();
        async_copy16(kseg + (size_t)kv0 * DXc,      ksl);
        async_copy16(kseg + (size_t)kv0 * DXc + 32, ksh);
        async_copy16(vseg + kv0,                    vtl);
        async_copy16(vseg + kv0 + 32,               vth);
        __syncthreads();

        // ---- QK phase: S^T blocks, exp2, pack, b64-write P^T ----
        f32x4 st[2][4];
        #pragma unroll
        for (int nb = 0; nb < 4; ++nb) {
            bf16x8 kf0 = *(const bf16x8*)(KsLo + (nb * 16 + l15) * 32 + quad * 8);
            bf16x8 kf1 = *(const bf16x8*)(KsHi + (nb * 16 + l15) * 32 + quad * 8);
            #pragma unroll
            for (int mi = 0; mi < 2; ++mi) {
                f32x4 z = {0.f, 0.f, 0.f, 0.f};
                z = MFMA_16x16x32(kf1, qf[mi][1], z);
                st[mi][nb] = MFMA_16x16x32(kf0, qf[mi][0], z);
            }
        }
        #pragma unroll
        for (int mi = 0; mi < 2; ++mi) {
            #pragma unroll
            for (int nb = 0; nb < 4; ++nb) {
                bf16x4 pt;
                #pragma unroll
                for (int r = 0; r < 4; ++r) {
                    float p = __builtin_exp2f(st[mi][nb][r]);
                    lsum[mi] += p;
                    pt[r] = (bf16)p;
                }
                *(bf16x4*)(&Pt[wave][mi][nb >> 1][0] + l15 * PST
                           + (nb & 1) * 16 + quad * 4) = pt;
            }
        }

        // ---- PV phase: K=32, A=Vt b128 frags, B=P^T b128 reads ----
        #pragma unroll
        for (int half = 0; half < 2; ++half) {
            const bf16* vb = half ? VtHi : VtLo;
            bf16x8 vtf[4];
            #pragma unroll
            for (int db = 0; db < 4; ++db)
                vtf[db] = *(const bf16x8*)(vb + (db * 16 + l15) * 32 + quad * 8);
            #pragma unroll
            for (int mi = 0; mi < 2; ++mi) {
                bf16x8 pf = *(const bf16x8*)(&Pt[wave][mi][half][0]
                                             + l15 * PST + quad * 8);
                #pragma unroll
                for (int db = 0; db < 4; ++db)
                    oacc[mi][db] = MFMA_16x16x32(vtf[db], pf, oacc[mi][db]);
            }
        }
    }

    // reduce lsum across quads (same qrow=l15 in all quads)
    #pragma unroll
    for (int mi = 0; mi < 2; ++mi) {
        lsum[mi] += __shfl_xor(lsum[mi], 16, 64);
        lsum[mi] += __shfl_xor(lsum[mi], 32, 64);
    }

    // epilogue: O^T — col=qrow=l15 (single inv), rows d contiguous bf16x4
    #pragma unroll
    for (int mi = 0; mi < 2; ++mi) {
        const float inv = 1.0f / lsum[mi];
        const int qrow = qt * 128 + wave * 32 + mi * 16 + l15;
        const bf16* rrow = QRp + qrbase + (size_t)qrow * QRST + 1024;
        bf16* orow = Op + obase + (size_t)qrow * DXc;
        #pragma unroll
        for (int db = 0; db < 4; ++db) {
            bf16x4 rg = *(const bf16x4*)(rrow + db * 16 + quad * 4);
            bf16x4 o;
            #pragma unroll
            for (int r = 0; r < 4; ++r)
                o[r] = (bf16)(oacc[mi][db][r] * inv * (float)rg[r]);
            *(bf16x4*)(orow + db * 16 + quad * 4) = o;
        }
    }
}

extern "C" void kernel_launch(void* const* d_in, const int* in_sizes, int n_in,
                              void* d_out, int out_size, void* d_ws, size_t ws_size,
                              hipStream_t stream)
{
    (void)in_sizes; (void)n_in; (void)out_size; (void)ws_size;
    constexpr int B = 4, S = 2048, DX = 1024, M = B * S;
    constexpr size_t MD = (size_t)M * DX;
    constexpr size_t WD = (size_t)DX * DX;

    const float* value  = (const float*)d_in[0];
    const float* keyi   = (const float*)d_in[1];
    const float* query  = (const float*)d_in[2];
    const float* Wq_w   = (const float*)d_in[3];
    const float* Wq_b   = (const float*)d_in[4];
    const float* Wk_w   = (const float*)d_in[5];
    const float* Wk_b   = (const float*)d_in[6];
    const float* Wv_w   = (const float*)d_in[7];
    const float* Wv_b   = (const float*)d_in[8];
    const float* Wr_w   = (const float*)d_in[9];
    const float* Wr_b   = (const float*)d_in[10];
    const float* Wout_w = (const float*)d_in[11];
    const float* Wout_b = (const float*)d_in[12];

    bf16* p = (bf16*)d_ws;
    bf16* xv   = p;  p += MD;
    bf16* xk   = p;  p += MD;
    bf16* xq   = p;  p += MD;
    bf16* wall = p;  p += 4 * WD;   // [Wq; Wr; Wk; Wv]
    bf16* wo   = p;  p += WD;
    bf16* qr   = p;  p += 2 * MD;   // fused Q|R, [M][2048]
    bf16* kws  = p;  p += MD;
    bf16* vtws = p;  p += MD;       // V^T: [B][DX][S]
    float* ball = (float*)p;        // packed bias [4096] f32
    bf16* ows = xv;                 // xv dead after projections

    hipMemcpyAsync(ball,            Wq_b, DX * sizeof(float), hipMemcpyDeviceToDevice, stream);
    hipMemcpyAsync(ball + DX,       Wr_b, DX * sizeof(float), hipMemcpyDeviceToDevice, stream);
    hipMemcpyAsync(ball + 2 * DX,   Wk_b, DX * sizeof(float), hipMemcpyDeviceToDevice, stream);
    hipMemcpyAsync(ball + 3 * DX,   Wv_b, DX * sizeof(float), hipMemcpyDeviceToDevice, stream);

    cvt3_acts<<<dim3(2048), dim3(256), 0, stream>>>(value, keyi, query, xv, xk, xq);
    cvt5_wts <<<dim3(1024), dim3(256), 0, stream>>>(Wq_w, Wr_w, Wk_w, Wv_w, Wout_w,
                                                    wall, wall + WD, wall + 2 * WD,
                                                    wall + 3 * WD, wo);

    proj_fused<<<dim3(M / 128, 32), dim3(256), 0, stream>>>(
        xq, xk, xv, wall, ball, qr, kws, vtws);

    attn_fused<<<dim3(S / 128, 16, B), dim3(256), 0, stream>>>(qr, kws, vtws, ows);

    gemm_out<<<dim3(M / 128, DX / 128), dim3(256), 0, stream>>>(
        ows, wo, Wout_b, (float*)d_out);
}